// Round 2
// baseline (117.922 us; speedup 1.0000x reference)
//
#include <hip/hip_runtime.h>

// yolov8 target: scores = max over 80 logit channels of (84, 336000) fp32;
// sum of top-2% scores + their 4 box coords (mask >= 0.2).
constexpr int N      = 336000;
constexpr int KSEL   = 6720;          // int(N * 0.02)
constexpr float CONFTH = 0.2f;

constexpr int NB   = 2048;            // histogram bins
constexpr int NSH  = 8;               // histogram shards (atomic contention)
constexpr float LO = -16.0f;
constexpr float BW = 32.0f / NB;      // 0.015625
constexpr float INV_BW = NB / 32.0f;  // 64
constexpr int MAXC = 4096;            // max boundary-bin candidates (expect ~370)

constexpr int K1_BLOCKS = (N + 255) / 256;   // 1313
constexpr int K2_BLOCKS = 512;

// meta[]: 0=b1  1=r  2=k1_counter  3=k2_counter  4=ncand  5=high_sum(float)

__device__ __forceinline__ int binOf(float s) {
  int b = (int)floorf((s - LO) * INV_BW);
  return b < 0 ? 0 : (b > NB - 1 ? NB - 1 : b);
}
__device__ __forceinline__ int aload(const int* p) {
  return __hip_atomic_load(p, __ATOMIC_RELAXED, __HIP_MEMORY_SCOPE_AGENT);
}
__device__ __forceinline__ float aloadf(const float* p) {
  return __hip_atomic_load(p, __ATOMIC_RELAXED, __HIP_MEMORY_SCOPE_AGENT);
}
__device__ __forceinline__ void astoref(float* p, float v) {
  __hip_atomic_store(p, v, __ATOMIC_RELAXED, __HIP_MEMORY_SCOPE_AGENT);
}
__device__ __forceinline__ void astorei(int* p, int v) {
  __hip_atomic_store(p, v, __ATOMIC_RELAXED, __HIP_MEMORY_SCOPE_AGENT);
}

// K1: scores + sharded histogram; last block scans -> (b1, r).
__global__ __launch_bounds__(256)
void k1_scores(const float* __restrict__ in, float* __restrict__ scores,
               int* __restrict__ hist, int* __restrict__ meta) {
  __shared__ int lh[NB];
  __shared__ int ssum[256];
  __shared__ int isLast;
  for (int i = threadIdx.x; i < NB; i += 256) lh[i] = 0;
  __syncthreads();

  const int gid = blockIdx.x * 256 + threadIdx.x;
  if (gid < N) {
    const int j = gid >> 2;   // float4 group of 4 anchors
    const int q = gid & 3;    // this lane covers channels [4+20q, 4+20q+20)
    const float* p = in + (size_t)(4 + 20 * q) * N + 4 * (size_t)j;
    float4 m = *(const float4*)p;
#pragma unroll
    for (int c = 1; c < 20; ++c) {
      float4 v = *(const float4*)(p + (size_t)c * N);
      m.x = fmaxf(m.x, v.x); m.y = fmaxf(m.y, v.y);
      m.z = fmaxf(m.z, v.z); m.w = fmaxf(m.w, v.w);
    }
    // butterfly max over the 4 lanes sharing this anchor group
#pragma unroll
    for (int d = 1; d < 4; d <<= 1) {
      m.x = fmaxf(m.x, __shfl_xor(m.x, d));
      m.y = fmaxf(m.y, __shfl_xor(m.y, d));
      m.z = fmaxf(m.z, __shfl_xor(m.z, d));
      m.w = fmaxf(m.w, __shfl_xor(m.w, d));
    }
    const float mv = (q & 2) ? ((q & 1) ? m.w : m.z) : ((q & 1) ? m.y : m.x);
    scores[gid] = mv;                       // lanes write consecutive -> coalesced
    atomicAdd(&lh[binOf(mv)], 1);
  }
  __syncthreads();

  int* shard = hist + (blockIdx.x & (NSH - 1)) * NB;
  for (int i = threadIdx.x; i < NB; i += 256) {
    int v = lh[i];
    if (v) atomicAdd(&shard[i], v);
  }

  __syncthreads();
  if (threadIdx.x == 0) {
    __threadfence();
    isLast = (atomicAdd(&meta[2], 1) == K1_BLOCKS - 1);
  }
  __syncthreads();
  if (!isLast) return;
  __threadfence();

  // ---- last block: hierarchical suffix scan of sharded hist ----
  const int t = threadIdx.x;
  const int base = t * (NB / 256);          // 8 bins per thread
  int csum = 0;
#pragma unroll
  for (int k = 0; k < NB / 256; ++k) {
    int bsum = 0;
#pragma unroll
    for (int s = 0; s < NSH; ++s) bsum += aload(&hist[s * NB + base + k]);
    csum += bsum;
  }
  ssum[t] = csum;
  __syncthreads();
  for (int d = 1; d < 256; d <<= 1) {
    int v = ssum[t] + ((t + d < 256) ? ssum[t + d] : 0);
    __syncthreads();
    ssum[t] = v;
    __syncthreads();
  }
  const int Sinc = ssum[t];
  const int Snext = (t < 255) ? ssum[t + 1] : 0;
  if (Sinc >= KSEL && Snext < KSEL) {       // exactly one thread
    int running = Snext;
    for (int k = NB / 256 - 1; k >= 0; --k) {
      int bsum = 0;
      for (int s = 0; s < NSH; ++s) bsum += aload(&hist[s * NB + base + k]);
      running += bsum;
      if (running >= KSEL) {
        meta[0] = base + k;                 // boundary bin
        meta[1] = KSEL - (running - bsum);  // top-r needed inside it (>=1)
        break;
      }
    }
  }
}

// K2: sum everything above the boundary bin; compact boundary-bin candidates;
// last block does exact top-r selection and writes out[0].
__global__ __launch_bounds__(256)
void k2_select(const float* __restrict__ in, const float* __restrict__ scores,
               int* __restrict__ meta, float* __restrict__ cscore,
               int* __restrict__ cidx, float* __restrict__ out) {
  __shared__ float cs[MAXC];
  __shared__ int   cx[MAXC];
  __shared__ float wred[4];
  __shared__ int isLast;

  const int b1 = meta[0];
  const float binlo = LO + b1 * BW;
  const float binhi = binlo + BW;

  float acc = 0.0f;
  for (int i = blockIdx.x * 256 + threadIdx.x; i < N; i += K2_BLOCKS * 256) {
    const float s = scores[i];
    if (s >= binhi) {
      if (s >= CONFTH)
        acc += s + in[i] + in[N + i] + in[2 * N + i] + in[3 * N + i];
    } else if (s >= binlo) {
      int p = atomicAdd(&meta[4], 1);
      if (p < MAXC) { astoref(&cscore[p], s); astorei(&cidx[p], i); }
    }
  }
  for (int off = 32; off > 0; off >>= 1) acc += __shfl_down(acc, off);
  if ((threadIdx.x & 63) == 0) wred[threadIdx.x >> 6] = acc;
  __syncthreads();
  if (threadIdx.x == 0) {
    atomicAdd((float*)&meta[5], wred[0] + wred[1] + wred[2] + wred[3]);
    __threadfence();
    isLast = (atomicAdd(&meta[3], 1) == K2_BLOCKS - 1);
  }
  __syncthreads();
  if (!isLast) return;
  __threadfence();

  // ---- last block: exact top-r among boundary-bin candidates ----
  const int r  = meta[1];
  const int nc = min(aload(&meta[4]), MAXC);
  for (int k = threadIdx.x; k < nc; k += 256) {
    cs[k] = aloadf(&cscore[k]);
    cx[k] = aload(&cidx[k]);
  }
  __syncthreads();

  float lacc = 0.0f;
  for (int ci = threadIdx.x; ci < nc; ci += 256) {
    const float si = cs[ci];
    const int ii = cx[ci];
    int rank = 0;
    for (int j = 0; j < nc; ++j) {
      const float sj = cs[j];
      rank += (sj > si) || (sj == si && cx[j] < ii);  // stable tie-break
    }
    if (rank < r && si >= CONFTH)
      lacc += si + in[ii] + in[N + ii] + in[2 * N + ii] + in[3 * N + ii];
  }
  for (int off = 32; off > 0; off >>= 1) lacc += __shfl_down(lacc, off);
  __syncthreads();
  if ((threadIdx.x & 63) == 0) wred[threadIdx.x >> 6] = lacc;
  __syncthreads();
  if (threadIdx.x == 0)
    out[0] = aloadf((float*)&meta[5]) + wred[0] + wred[1] + wred[2] + wred[3];
}

extern "C" void kernel_launch(void* const* d_in, const int* in_sizes, int n_in,
                              void* d_out, int out_size, void* d_ws, size_t ws_size,
                              hipStream_t stream) {
  const float* in = (const float*)d_in[0];
  float* out = (float*)d_out;

  // ws: hist[NSH*NB] | meta[16] | cscore[MAXC] | cidx[MAXC] | scores[N]
  int* hist = (int*)d_ws;
  int* meta = hist + NSH * NB;
  float* cscore = (float*)(meta + 16);
  int* cidx = (int*)(cscore + MAXC);
  float* scores = (float*)(cidx + MAXC);

  hipMemsetAsync(hist, 0, (NSH * NB + 16) * sizeof(int), stream);
  k1_scores<<<K1_BLOCKS, 256, 0, stream>>>(in, scores, hist, meta);
  k2_select<<<K2_BLOCKS, 256, 0, stream>>>(in, scores, meta, cscore, cidx, out);
}

// Round 3
// 94.205 us; speedup vs baseline: 1.2518x; 1.2518x over previous
//
#include <hip/hip_runtime.h>

// yolov8 target: scores = max over 80 logit channels of (84, 336000) fp32;
// sum of top-2% (k=6720) scores + their 4 box coords (mask >= 0.2).
constexpr int N      = 336000;
constexpr int NG     = N / 4;         // 84000 float4 anchor groups
constexpr int KSEL   = 6720;          // int(N * 0.02)
constexpr float CONFTH = 0.2f;

constexpr int NB   = 2048;            // histogram bins
constexpr int NSH  = 8;               // histogram shards (atomic contention)
constexpr float LO = -16.0f;
constexpr float BW = 32.0f / NB;      // 0.015625
constexpr float INV_BW = NB / 32.0f;  // 64
constexpr int MAXC = 4096;            // boundary-bin candidates (expect ~360)

constexpr int K1_TPB    = 128;
constexpr int K1_BLOCKS = (NG + K1_TPB - 1) / K1_TPB;   // 657
constexpr int K2_BLOCKS = 512;

// meta[]: 0=b1  1=r  2=k1_counter  3=k2_counter  4=ncand  5=high_sum(float)

__device__ __forceinline__ int binOf(float s) {
  int b = (int)floorf((s - LO) * INV_BW);
  return b < 0 ? 0 : (b > NB - 1 ? NB - 1 : b);
}
__device__ __forceinline__ int aload(const int* p) {
  return __hip_atomic_load(p, __ATOMIC_RELAXED, __HIP_MEMORY_SCOPE_AGENT);
}
__device__ __forceinline__ float aloadf(const float* p) {
  return __hip_atomic_load(p, __ATOMIC_RELAXED, __HIP_MEMORY_SCOPE_AGENT);
}
__device__ __forceinline__ void astoref(float* p, float v) {
  __hip_atomic_store(p, v, __ATOMIC_RELAXED, __HIP_MEMORY_SCOPE_AGENT);
}
__device__ __forceinline__ void astorei(int* p, int v) {
  __hip_atomic_store(p, v, __ATOMIC_RELAXED, __HIP_MEMORY_SCOPE_AGENT);
}

// K1: thread = one float4 group of 4 anchors; 80 coalesced 1KB wave-loads.
// Sharded global histogram; last block scans -> (b1, r).
__global__ __launch_bounds__(K1_TPB)
void k1_scores(const float* __restrict__ in, float* __restrict__ scores,
               int* __restrict__ hist, int* __restrict__ meta) {
  __shared__ int lh[NB];
  __shared__ int ssum[K1_TPB];
  __shared__ int isLast;
  for (int i = threadIdx.x; i < NB; i += K1_TPB) lh[i] = 0;
  __syncthreads();

  const int j = blockIdx.x * K1_TPB + threadIdx.x;
  if (j < NG) {
    const float* p = in + (size_t)4 * N + 4 * (size_t)j;
    float4 m = *(const float4*)p;
#pragma unroll 8
    for (int c = 1; c < 80; ++c) {
      float4 v = *(const float4*)(p + (size_t)c * N);
      m.x = fmaxf(m.x, v.x); m.y = fmaxf(m.y, v.y);
      m.z = fmaxf(m.z, v.z); m.w = fmaxf(m.w, v.w);
    }
    *(float4*)(scores + 4 * j) = m;
    atomicAdd(&lh[binOf(m.x)], 1);
    atomicAdd(&lh[binOf(m.y)], 1);
    atomicAdd(&lh[binOf(m.z)], 1);
    atomicAdd(&lh[binOf(m.w)], 1);
  }
  __syncthreads();

  int* shard = hist + (blockIdx.x & (NSH - 1)) * NB;
  for (int i = threadIdx.x; i < NB; i += K1_TPB) {
    int v = lh[i];
    if (v) atomicAdd(&shard[i], v);
  }

  __syncthreads();
  if (threadIdx.x == 0) {
    __threadfence();
    isLast = (atomicAdd(&meta[2], 1) == K1_BLOCKS - 1);
  }
  __syncthreads();
  if (!isLast) return;
  __threadfence();

  // ---- last block: hierarchical suffix scan of sharded hist ----
  const int t = threadIdx.x;
  constexpr int BPT = NB / K1_TPB;          // 16 bins per thread
  const int base = t * BPT;
  int csum = 0;
#pragma unroll
  for (int k = 0; k < BPT; ++k) {
    int bsum = 0;
#pragma unroll
    for (int s = 0; s < NSH; ++s) bsum += aload(&hist[s * NB + base + k]);
    csum += bsum;
  }
  ssum[t] = csum;
  __syncthreads();
  for (int d = 1; d < K1_TPB; d <<= 1) {
    int v = ssum[t] + ((t + d < K1_TPB) ? ssum[t + d] : 0);
    __syncthreads();
    ssum[t] = v;
    __syncthreads();
  }
  const int Sinc = ssum[t];
  const int Snext = (t < K1_TPB - 1) ? ssum[t + 1] : 0;
  if (Sinc >= KSEL && Snext < KSEL) {       // exactly one thread
    int running = Snext;
    for (int k = BPT - 1; k >= 0; --k) {
      int bsum = 0;
      for (int s = 0; s < NSH; ++s) bsum += aload(&hist[s * NB + base + k]);
      running += bsum;
      if (running >= KSEL) {
        meta[0] = base + k;                 // boundary bin
        meta[1] = KSEL - (running - bsum);  // top-r needed inside it (>=1)
        break;
      }
    }
  }
}

// K2: sum everything above the boundary bin; compact boundary-bin candidates;
// last block does exact top-r selection and writes out[0].
__global__ __launch_bounds__(256)
void k2_select(const float* __restrict__ in, const float* __restrict__ scores,
               int* __restrict__ meta, float* __restrict__ cscore,
               int* __restrict__ cidx, float* __restrict__ out) {
  __shared__ float cs[MAXC];
  __shared__ int   cx[MAXC];
  __shared__ float wred[4];
  __shared__ int isLast;

  const int b1 = meta[0];
  const float binlo = LO + b1 * BW;
  const float binhi = binlo + BW;

  float acc = 0.0f;
  for (int i = blockIdx.x * 256 + threadIdx.x; i < N; i += K2_BLOCKS * 256) {
    const float s = scores[i];
    if (s >= binhi) {
      if (s >= CONFTH)
        acc += s + in[i] + in[N + i] + in[2 * N + i] + in[3 * N + i];
    } else if (s >= binlo) {
      int p = atomicAdd(&meta[4], 1);
      if (p < MAXC) { astoref(&cscore[p], s); astorei(&cidx[p], i); }
    }
  }
  for (int off = 32; off > 0; off >>= 1) acc += __shfl_down(acc, off);
  if ((threadIdx.x & 63) == 0) wred[threadIdx.x >> 6] = acc;
  __syncthreads();
  if (threadIdx.x == 0) {
    atomicAdd((float*)&meta[5], wred[0] + wred[1] + wred[2] + wred[3]);
    __threadfence();
    isLast = (atomicAdd(&meta[3], 1) == K2_BLOCKS - 1);
  }
  __syncthreads();
  if (!isLast) return;
  __threadfence();

  // ---- last block: exact top-r among boundary-bin candidates ----
  const int r  = meta[1];
  const int nc = min(aload(&meta[4]), MAXC);
  for (int k = threadIdx.x; k < nc; k += 256) {
    cs[k] = aloadf(&cscore[k]);
    cx[k] = aload(&cidx[k]);
  }
  __syncthreads();

  float lacc = 0.0f;
  for (int ci = threadIdx.x; ci < nc; ci += 256) {
    const float si = cs[ci];
    const int ii = cx[ci];
    int rank = 0;
    for (int jj = 0; jj < nc; ++jj) {
      const float sj = cs[jj];
      rank += (sj > si) || (sj == si && cx[jj] < ii);  // stable tie-break
    }
    if (rank < r && si >= CONFTH)
      lacc += si + in[ii] + in[N + ii] + in[2 * N + ii] + in[3 * N + ii];
  }
  for (int off = 32; off > 0; off >>= 1) lacc += __shfl_down(lacc, off);
  __syncthreads();
  if ((threadIdx.x & 63) == 0) wred[threadIdx.x >> 6] = lacc;
  __syncthreads();
  if (threadIdx.x == 0)
    out[0] = aloadf((float*)&meta[5]) + wred[0] + wred[1] + wred[2] + wred[3];
}

extern "C" void kernel_launch(void* const* d_in, const int* in_sizes, int n_in,
                              void* d_out, int out_size, void* d_ws, size_t ws_size,
                              hipStream_t stream) {
  const float* in = (const float*)d_in[0];
  float* out = (float*)d_out;

  // ws: hist[NSH*NB] | meta[16] | cscore[MAXC] | cidx[MAXC] | scores[N]
  int* hist = (int*)d_ws;
  int* meta = hist + NSH * NB;
  float* cscore = (float*)(meta + 16);
  int* cidx = (int*)(cscore + MAXC);
  float* scores = (float*)(cidx + MAXC);

  hipMemsetAsync(hist, 0, (NSH * NB + 16) * sizeof(int), stream);
  k1_scores<<<K1_BLOCKS, K1_TPB, 0, stream>>>(in, scores, hist, meta);
  k2_select<<<K2_BLOCKS, 256, 0, stream>>>(in, scores, meta, cscore, cidx, out);
}

// Round 4
// 65.332 us; speedup vs baseline: 1.8050x; 1.4420x over previous
//
#include <hip/hip_runtime.h>

// yolov8 target: scores = max over 80 logit channels of (84, 336000) fp32;
// sum of top-2% (k=6720) scores + their 4 box coords (mask >= 0.2).
constexpr int N      = 336000;
constexpr int NG     = N / 4;         // 84000 float4 anchor groups
constexpr int KSEL   = 6720;          // int(N * 0.02)
constexpr float CONFTH = 0.2f;

constexpr int NB   = 2048;            // histogram bins
constexpr int NSH  = 8;               // histogram shards (atomic contention)
constexpr float LO = -16.0f;
constexpr float BW = 32.0f / NB;      // 0.015625
constexpr float INV_BW = NB / 32.0f;  // 64
constexpr int MAXC = 4096;            // boundary-bin candidates (expect ~360)

constexpr int K1_TPB    = 128;
constexpr int K1_BLOCKS = (NG + K1_TPB - 1) / K1_TPB;   // 657
constexpr int K3_BLOCKS = (NG + 255) / 256;             // 329

// meta[]: 0=b1  1=r  2=unused  3=k3_counter  4=ncand  5=high_sum(float)

__device__ __forceinline__ int binOf(float s) {
  int b = (int)floorf((s - LO) * INV_BW);
  return b < 0 ? 0 : (b > NB - 1 ? NB - 1 : b);
}
__device__ __forceinline__ int aload(const int* p) {
  return __hip_atomic_load(p, __ATOMIC_RELAXED, __HIP_MEMORY_SCOPE_AGENT);
}
__device__ __forceinline__ float aloadf(const float* p) {
  return __hip_atomic_load(p, __ATOMIC_RELAXED, __HIP_MEMORY_SCOPE_AGENT);
}
__device__ __forceinline__ void astoref(float* p, float v) {
  __hip_atomic_store(p, v, __ATOMIC_RELAXED, __HIP_MEMORY_SCOPE_AGENT);
}
__device__ __forceinline__ void astorei(int* p, int v) {
  __hip_atomic_store(p, v, __ATOMIC_RELAXED, __HIP_MEMORY_SCOPE_AGENT);
}

// K1: pure streaming. thread = one float4 group of 4 anchors; 5 rounds of
// 16 explicit in-flight float4 loads (MLP=16). LDS hist -> sharded global.
__global__ __launch_bounds__(K1_TPB)
void k1_scores(const float* __restrict__ in, float* __restrict__ scores,
               int* __restrict__ hist) {
  __shared__ int lh[NB];
  for (int i = threadIdx.x; i < NB; i += K1_TPB) lh[i] = 0;
  __syncthreads();

  const int j = blockIdx.x * K1_TPB + threadIdx.x;
  if (j < NG) {
    const float* p = in + (size_t)4 * N + 4 * (size_t)j;
    float4 m = make_float4(-1e30f, -1e30f, -1e30f, -1e30f);
#pragma unroll
    for (int round = 0; round < 5; ++round) {
      float4 v[16];
#pragma unroll
      for (int u = 0; u < 16; ++u)
        v[u] = *(const float4*)(p + (size_t)(round * 16 + u) * N);
#pragma unroll
      for (int u = 0; u < 16; ++u) {
        m.x = fmaxf(m.x, v[u].x); m.y = fmaxf(m.y, v[u].y);
        m.z = fmaxf(m.z, v[u].z); m.w = fmaxf(m.w, v[u].w);
      }
    }
    *(float4*)(scores + 4 * j) = m;
    atomicAdd(&lh[binOf(m.x)], 1);
    atomicAdd(&lh[binOf(m.y)], 1);
    atomicAdd(&lh[binOf(m.z)], 1);
    atomicAdd(&lh[binOf(m.w)], 1);
  }
  __syncthreads();

  int* shard = hist + (blockIdx.x & (NSH - 1)) * NB;
  for (int i = threadIdx.x; i < NB; i += K1_TPB) {
    int v = lh[i];
    if (v) atomicAdd(&shard[i], v);
  }
}

// K2: single block, coalesced vectorized shard-sum + suffix scan -> (b1, r).
__global__ __launch_bounds__(256)
void k2_scan(const int* __restrict__ hist, int* __restrict__ meta) {
  __shared__ int ssum[256];
  const int t = threadIdx.x;
  int bs[8] = {0, 0, 0, 0, 0, 0, 0, 0};
#pragma unroll
  for (int s = 0; s < NSH; ++s) {
    const int4* hp = (const int4*)(hist + s * NB + 8 * t);
    int4 x = hp[0], y = hp[1];
    bs[0] += x.x; bs[1] += x.y; bs[2] += x.z; bs[3] += x.w;
    bs[4] += y.x; bs[5] += y.y; bs[6] += y.z; bs[7] += y.w;
  }
  int tot = 0;
#pragma unroll
  for (int k = 0; k < 8; ++k) tot += bs[k];
  ssum[t] = tot;
  __syncthreads();
  for (int d = 1; d < 256; d <<= 1) {
    int v = ssum[t] + ((t + d < 256) ? ssum[t + d] : 0);
    __syncthreads();
    ssum[t] = v;
    __syncthreads();
  }
  const int Sinc = ssum[t];
  const int Snext = (t < 255) ? ssum[t + 1] : 0;
  if (Sinc >= KSEL && Snext < KSEL) {       // exactly one thread
    int running = Snext;
#pragma unroll
    for (int k = 7; k >= 0; --k) {
      running += bs[k];
      if (running >= KSEL) {
        meta[0] = 8 * t + k;                // boundary bin
        meta[1] = KSEL - (running - bs[k]); // top-r needed inside it (>=1)
        break;
      }
    }
  }
}

// K3: sum everything above the boundary bin; compact boundary-bin candidates;
// last block does exact top-r selection and writes out[0].
__global__ __launch_bounds__(256)
void k3_select(const float* __restrict__ in, const float* __restrict__ scores,
               int* __restrict__ meta, float* __restrict__ cscore,
               int* __restrict__ cidx, float* __restrict__ out) {
  __shared__ float cs[MAXC];
  __shared__ int   cx[MAXC];
  __shared__ float wred[4];
  __shared__ int isLast;

  const int b1 = meta[0];
  const float binlo = LO + b1 * BW;
  const float binhi = binlo + BW;

  float acc = 0.0f;
  const int g = blockIdx.x * 256 + threadIdx.x;
  if (g < NG) {
    const float4 s4 = ((const float4*)scores)[g];
    const float v[4] = {s4.x, s4.y, s4.z, s4.w};
#pragma unroll
    for (int q = 0; q < 4; ++q) {
      const float s = v[q];
      const int i = 4 * g + q;
      if (s >= binhi) {
        if (s >= CONFTH)
          acc += s + in[i] + in[N + i] + in[2 * N + i] + in[3 * N + i];
      } else if (s >= binlo) {
        int p = atomicAdd(&meta[4], 1);
        if (p < MAXC) { astoref(&cscore[p], s); astorei(&cidx[p], i); }
      }
    }
  }
  for (int off = 32; off > 0; off >>= 1) acc += __shfl_down(acc, off);
  if ((threadIdx.x & 63) == 0) wred[threadIdx.x >> 6] = acc;
  __syncthreads();
  if (threadIdx.x == 0) {
    atomicAdd((float*)&meta[5], wred[0] + wred[1] + wred[2] + wred[3]);
    __threadfence();
    isLast = (atomicAdd(&meta[3], 1) == K3_BLOCKS - 1);
  }
  __syncthreads();
  if (!isLast) return;
  __threadfence();

  // ---- last block: exact top-r among boundary-bin candidates ----
  const int r  = meta[1];
  const int nc = min(aload(&meta[4]), MAXC);
  for (int k = threadIdx.x; k < nc; k += 256) {
    cs[k] = aloadf(&cscore[k]);
    cx[k] = aload(&cidx[k]);
  }
  __syncthreads();

  float lacc = 0.0f;
  for (int ci = threadIdx.x; ci < nc; ci += 256) {
    const float si = cs[ci];
    const int ii = cx[ci];
    int rank = 0;
    for (int jj = 0; jj < nc; ++jj) {
      const float sj = cs[jj];
      rank += (sj > si) || (sj == si && cx[jj] < ii);  // stable tie-break
    }
    if (rank < r && si >= CONFTH)
      lacc += si + in[ii] + in[N + ii] + in[2 * N + ii] + in[3 * N + ii];
  }
  for (int off = 32; off > 0; off >>= 1) lacc += __shfl_down(lacc, off);
  __syncthreads();
  if ((threadIdx.x & 63) == 0) wred[threadIdx.x >> 6] = lacc;
  __syncthreads();
  if (threadIdx.x == 0)
    out[0] = aloadf((float*)&meta[5]) + wred[0] + wred[1] + wred[2] + wred[3];
}

extern "C" void kernel_launch(void* const* d_in, const int* in_sizes, int n_in,
                              void* d_out, int out_size, void* d_ws, size_t ws_size,
                              hipStream_t stream) {
  const float* in = (const float*)d_in[0];
  float* out = (float*)d_out;

  // ws: hist[NSH*NB] | meta[16] | cscore[MAXC] | cidx[MAXC] | scores[N]
  int* hist = (int*)d_ws;
  int* meta = hist + NSH * NB;
  float* cscore = (float*)(meta + 16);
  int* cidx = (int*)(cscore + MAXC);
  float* scores = (float*)(cidx + MAXC);

  hipMemsetAsync(hist, 0, (NSH * NB + 16) * sizeof(int), stream);
  k1_scores<<<K1_BLOCKS, K1_TPB, 0, stream>>>(in, scores, hist);
  k2_scan<<<1, 256, 0, stream>>>(hist, meta);
  k3_select<<<K3_BLOCKS, 256, 0, stream>>>(in, scores, meta, cscore, cidx, out);
}